// Round 8
// baseline (406.082 us; speedup 1.0000x reference)
//
#include <hip/hip_runtime.h>
#include <hip/hip_cooperative_groups.h>

namespace cg = cooperative_groups;

constexpr int N_  = 64;
constexpr int C_  = 256;
constexpr int HW_ = 56 * 56;      // 3136
constexpr int NV_ = HW_ / 4;      // 784 f32x4 per slice
constexpr int G_  = 32;
constexpr int NC_ = N_ * C_;      // 16384
constexpr float EPS_ = 1e-5f;

typedef float f32x4 __attribute__((ext_vector_type(4)));

// ============================ fused cooperative kernel ============================
// 256 threads (4 waves) per block; grid-stride phases so ANY grid size is correct.
// Phase1: wave-per-slice sums -> s1,s2.  Phase2a: block-per-channel logits+argmax.
// Phase2b: block-per-n group stats -> scale/shift in ws.  Phase3: wave-per-slice
// normalize (x re-read, L3-warm), NT stores.
__global__ __launch_bounds__(256, 4) void k_fused(
    const float* __restrict__ x,
    const float* __restrict__ fc_w,
    const float* __restrict__ fc_b,
    const float* __restrict__ weight,
    const float* __restrict__ bias,
    float* __restrict__ out,
    float* __restrict__ s1,
    float* __restrict__ s2,
    float* __restrict__ scale,
    float* __restrict__ shift,
    int*   __restrict__ gidxg)
{
    const int t    = threadIdx.x;
    const int w    = t >> 6;
    const int lane = t & 63;
    const int nwaves = gridDim.x * 4;

    __shared__ float r1s[C_], r2s[C_];
    __shared__ int   gidxL[C_];
    __shared__ float mgs[G_], igs[G_];

    // ---------------- Phase 1: per-slice sums ----------------
    for (int nc = blockIdx.x * 4 + w; nc < NC_; nc += nwaves) {
        const f32x4* xp = reinterpret_cast<const f32x4*>(x) + (size_t)nc * NV_;
        f32x4 v[12];
        #pragma unroll
        for (int k = 0; k < 12; ++k) v[k] = xp[lane + k * 64];
        const bool tail = lane < 16;
        f32x4 vt;
        if (tail) vt = xp[768 + lane];
        float a = 0.f, q = 0.f;
        #pragma unroll
        for (int k = 0; k < 12; ++k) {
            a += (v[k].x + v[k].y) + (v[k].z + v[k].w);
            q += (v[k].x * v[k].x + v[k].y * v[k].y) + (v[k].z * v[k].z + v[k].w * v[k].w);
        }
        if (tail) {
            a += (vt.x + vt.y) + (vt.z + vt.w);
            q += (vt.x * vt.x + vt.y * vt.y) + (vt.z * vt.z + vt.w * vt.w);
        }
        #pragma unroll
        for (int off = 32; off; off >>= 1) {
            a += __shfl_down(a, off, 64);
            q += __shfl_down(q, off, 64);
        }
        if (lane == 0) {
            __hip_atomic_store(&s1[nc], a, __ATOMIC_RELAXED, __HIP_MEMORY_SCOPE_AGENT);
            __hip_atomic_store(&s2[nc], q, __ATOMIC_RELAXED, __HIP_MEMORY_SCOPE_AGENT);
        }
    }

    __threadfence();
    cg::this_grid().sync();

    // ---------------- Phase 2a: per-channel logits + first-occurrence argmax ----------------
    for (int c = blockIdx.x; c < C_; c += gridDim.x) {
        if (t < 64) {
            const int g = lane & 31, half = lane >> 5;
            const float inv_hw  = 1.f / (float)HW_;
            const float inv_hw1 = 1.f / (float)(HW_ - 1);
            const float* wg = fc_w + g * (2 * N_);
            float acc = half ? 0.f : fc_b[g];
            const int n0 = half * 32;
            #pragma unroll
            for (int nn = n0; nn < n0 + 32; ++nn) {
                const float a1 = __hip_atomic_load(&s1[nn * C_ + c], __ATOMIC_RELAXED, __HIP_MEMORY_SCOPE_AGENT);
                const float a2 = __hip_atomic_load(&s2[nn * C_ + c], __ATOMIC_RELAXED, __HIP_MEMORY_SCOPE_AGENT);
                const float m  = a1 * inv_hw;
                const float vr = (a2 - a1 * m) * inv_hw1;   // ddof=1
                acc += m * wg[nn] + vr * wg[N_ + nn];
            }
            acc += __shfl_down(acc, 32, 64);
            float bv = acc; int bi = g;
            #pragma unroll
            for (int off = 16; off; off >>= 1) {
                float ov = __shfl_down(bv, off, 32);
                int   oi = __shfl_down(bi, off, 32);
                if (ov > bv || (ov == bv && oi < bi)) { bv = ov; bi = oi; }
            }
            if (lane == 0)
                __hip_atomic_store(&gidxg[c], bi, __ATOMIC_RELAXED, __HIP_MEMORY_SCOPE_AGENT);
        }
    }

    __threadfence();
    cg::this_grid().sync();

    // ---------------- Phase 2b: per-n group stats -> scale/shift (to ws) ----------------
    for (int n = blockIdx.x; n < N_; n += gridDim.x) {
        __syncthreads();
        r1s[t]   = __hip_atomic_load(&s1[n * C_ + t], __ATOMIC_RELAXED, __HIP_MEMORY_SCOPE_AGENT);
        r2s[t]   = __hip_atomic_load(&s2[n * C_ + t], __ATOMIC_RELAXED, __HIP_MEMORY_SCOPE_AGENT);
        gidxL[t] = __hip_atomic_load(&gidxg[t],       __ATOMIC_RELAXED, __HIP_MEMORY_SCOPE_AGENT);
        __syncthreads();
        if (t < G_) {
            float A = 0.f, B = 0.f; int k = 0;
            for (int cc = 0; cc < C_; ++cc)
                if (gidxL[cc] == t) { A += r1s[cc]; B += r2s[cc]; ++k; }
            const float cf = (float)k * (float)HW_;
            const float m  = A / fmaxf(cf, 1.f);
            const float vr = (B - A * m) / fmaxf(cf - 1.f, 1.f);
            mgs[t] = m;
            igs[t] = rsqrtf(vr + EPS_);
        }
        __syncthreads();
        {
            const int c = t;
            const int g = gidxL[c];
            const float sc = igs[g] * weight[c];
            __hip_atomic_store(&scale[n * C_ + c], sc, __ATOMIC_RELAXED, __HIP_MEMORY_SCOPE_AGENT);
            __hip_atomic_store(&shift[n * C_ + c], bias[c] - mgs[g] * sc, __ATOMIC_RELAXED, __HIP_MEMORY_SCOPE_AGENT);
        }
    }

    __threadfence();
    cg::this_grid().sync();

    // ---------------- Phase 3: normalize (x re-read, L3-warm), NT stores ----------------
    for (int nc = blockIdx.x * 4 + w; nc < NC_; nc += nwaves) {
        const float sc = __hip_atomic_load(&scale[nc], __ATOMIC_RELAXED, __HIP_MEMORY_SCOPE_AGENT);
        const float sh = __hip_atomic_load(&shift[nc], __ATOMIC_RELAXED, __HIP_MEMORY_SCOPE_AGENT);
        const f32x4* xp = reinterpret_cast<const f32x4*>(x)  + (size_t)nc * NV_;
        f32x4*       op = reinterpret_cast<f32x4*>(out)      + (size_t)nc * NV_;
        f32x4 v[12];
        #pragma unroll
        for (int k = 0; k < 12; ++k) v[k] = xp[lane + k * 64];
        const bool tail = lane < 16;
        f32x4 vt;
        if (tail) vt = xp[768 + lane];
        #pragma unroll
        for (int k = 0; k < 12; ++k)
            __builtin_nontemporal_store(v[k] * sc + sh, op + lane + k * 64);
        if (tail)
            __builtin_nontemporal_store(vt * sc + sh, op + 768 + lane);
    }
}

// ============================ fallback split kernels (r5, proven) ============================
__global__ __launch_bounds__(256) void k_sums(const float* __restrict__ x,
                                              float* __restrict__ s1,
                                              float* __restrict__ s2) {
    const int wave = threadIdx.x >> 6;
    const int lane = threadIdx.x & 63;
    const int nc = blockIdx.x * 4 + wave;
    const f32x4* xp = reinterpret_cast<const f32x4*>(x + (size_t)nc * HW_);
    f32x4 v[12];
    #pragma unroll
    for (int k = 0; k < 12; ++k) v[k] = xp[lane + k * 64];
    f32x4 vt;
    const bool tail = lane < 16;
    if (tail) vt = xp[768 + lane];
    float a = 0.f, b = 0.f;
    #pragma unroll
    for (int k = 0; k < 12; ++k) {
        a += (v[k].x + v[k].y) + (v[k].z + v[k].w);
        b += (v[k].x * v[k].x + v[k].y * v[k].y) + (v[k].z * v[k].z + v[k].w * v[k].w);
    }
    if (tail) {
        a += (vt.x + vt.y) + (vt.z + vt.w);
        b += (vt.x * vt.x + vt.y * vt.y) + (vt.z * vt.z + vt.w * vt.w);
    }
    #pragma unroll
    for (int off = 32; off; off >>= 1) {
        a += __shfl_down(a, off, 64);
        b += __shfl_down(b, off, 64);
    }
    if (lane == 0) { s1[nc] = a; s2[nc] = b; }
}

__global__ __launch_bounds__(64) void k_logits(const float* __restrict__ s1,
                                               const float* __restrict__ s2,
                                               const float* __restrict__ fc_w,
                                               const float* __restrict__ fc_b,
                                               int* __restrict__ gidx) {
    const int c = blockIdx.x;
    const int t = threadIdx.x;
    const int g = t & 31, half = t >> 5;
    const float inv_hw  = 1.f / (float)HW_;
    const float inv_hw1 = 1.f / (float)(HW_ - 1);
    const float* wg = fc_w + g * (2 * N_);
    float acc = half ? 0.f : fc_b[g];
    const int n0 = half * 32;
    #pragma unroll 8
    for (int n = n0; n < n0 + 32; ++n) {
        const float v1 = s1[n * C_ + c];
        const float v2 = s2[n * C_ + c];
        const float m  = v1 * inv_hw;
        const float vr = (v2 - v1 * m) * inv_hw1;
        acc += m * wg[n] + vr * wg[N_ + n];
    }
    acc += __shfl_down(acc, 32, 64);
    __shared__ float lg[G_];
    if (half == 0) lg[g] = acc;
    __syncthreads();
    if (t == 0) {
        float best = lg[0];
        int bi = 0;
        for (int g2 = 1; g2 < G_; ++g2) {
            const float v = lg[g2];
            if (v > best) { best = v; bi = g2; }
        }
        gidx[c] = bi;
    }
}

__global__ __launch_bounds__(256) void k_group(const float* __restrict__ s1,
                                               const float* __restrict__ s2,
                                               const int* __restrict__ gidx,
                                               const float* __restrict__ weight,
                                               const float* __restrict__ bias,
                                               float* __restrict__ scale,
                                               float* __restrict__ shift) {
    const int n = blockIdx.x;
    const int c = threadIdx.x;
    __shared__ float r1[C_], r2[C_];
    __shared__ int   gi[C_];
    __shared__ float mg[G_], ig[G_];
    r1[c] = s1[n * C_ + c];
    r2[c] = s2[n * C_ + c];
    gi[c] = gidx[c];
    __syncthreads();
    if (c < G_) {
        float A = 0.f, B = 0.f;
        int k = 0;
        for (int cc = 0; cc < C_; ++cc) {
            if (gi[cc] == c) { A += r1[cc]; B += r2[cc]; ++k; }
        }
        const float cf = (float)k * (float)HW_;
        const float m  = A / fmaxf(cf, 1.f);
        const float vr = (B - A * m) / fmaxf(cf - 1.f, 1.f);
        mg[c] = m;
        ig[c] = rsqrtf(vr + EPS_);
    }
    __syncthreads();
    const int g = gi[c];
    const float sc = ig[g] * weight[c];
    scale[n * C_ + c] = sc;
    shift[n * C_ + c] = bias[c] - mg[g] * sc;
}

__global__ __launch_bounds__(256) void k_norm(const float* __restrict__ x,
                                              const float* __restrict__ scale,
                                              const float* __restrict__ shift,
                                              float* __restrict__ out) {
    const int wave = threadIdx.x >> 6;
    const int lane = threadIdx.x & 63;
    const int nc = blockIdx.x * 4 + wave;
    const float sc = scale[nc];
    const float sh = shift[nc];
    const f32x4* xp = reinterpret_cast<const f32x4*>(x + (size_t)nc * HW_);
    f32x4* op = reinterpret_cast<f32x4*>(out + (size_t)nc * HW_);
    f32x4 v[12];
    #pragma unroll
    for (int k = 0; k < 12; ++k) v[k] = xp[lane + k * 64];
    f32x4 vt;
    const bool tail = lane < 16;
    if (tail) vt = xp[768 + lane];
    #pragma unroll
    for (int k = 0; k < 12; ++k)
        __builtin_nontemporal_store(v[k] * sc + sh, op + lane + k * 64);
    if (tail)
        __builtin_nontemporal_store(vt * sc + sh, op + 768 + lane);
}

extern "C" void kernel_launch(void* const* d_in, const int* in_sizes, int n_in,
                              void* d_out, int out_size, void* d_ws, size_t ws_size,
                              hipStream_t stream) {
    const float* x      = (const float*)d_in[0];
    const float* fc_w   = (const float*)d_in[1];
    const float* fc_b   = (const float*)d_in[2];
    const float* weight = (const float*)d_in[3];
    const float* bias   = (const float*)d_in[4];
    float* outp = (float*)d_out;

    float* ws    = (float*)d_ws;
    float* s1    = ws;
    float* s2    = ws + NC_;
    float* scale = ws + 2 * NC_;
    float* shift = ws + 3 * NC_;
    int*   gidxg = (int*)(ws + 4 * NC_);

    // Host-side occupancy query (capture-safe, deterministic): clamp coop grid.
    int bpc = 0;
    hipError_t oe = hipOccupancyMaxActiveBlocksPerMultiprocessor(&bpc, k_fused, 256, 0);
    int grid = 0;
    if (oe == hipSuccess && bpc > 0) {
        grid = bpc * 256;               // 256 CUs on MI355X
        if (grid > 1024) grid = 1024;
    }

    if (grid >= 64) {
        void* args[] = { (void*)&x, (void*)&fc_w, (void*)&fc_b, (void*)&weight, (void*)&bias,
                         (void*)&outp, (void*)&s1, (void*)&s2, (void*)&scale, (void*)&shift,
                         (void*)&gidxg };
        hipLaunchCooperativeKernel((void*)k_fused, dim3(grid), dim3(256), args, 0, stream);
    } else {
        k_sums  <<<NC_ / 4, 256, 0, stream>>>(x, s1, s2);
        k_logits<<<C_,       64, 0, stream>>>(s1, s2, fc_w, fc_b, gidxg);
        k_group <<<N_,      256, 0, stream>>>(s1, s2, gidxg, weight, bias, scale, shift);
        k_norm  <<<NC_ / 4, 256, 0, stream>>>(x, scale, shift, outp);
    }
}

// Round 9
// 128.447 us; speedup vs baseline: 3.1615x; 3.1615x over previous
//
#include <hip/hip_runtime.h>

constexpr int N_  = 64;
constexpr int C_  = 256;
constexpr int HW_ = 56 * 56;      // 3136 floats per slice
constexpr int NV_ = HW_ / 4;      // 784 f32x4 per slice
constexpr int G_  = 32;
constexpr int NC_ = N_ * C_;      // 16384
constexpr float EPS_ = 1e-5f;

typedef float f32x4 __attribute__((ext_vector_type(4)));

// ---------------- Kernel 1: per-(n,c) sum & sumsq — one wave per slice ----------------
__global__ __launch_bounds__(256) void k_sums(const float* __restrict__ x,
                                              float* __restrict__ s1,
                                              float* __restrict__ s2) {
    const int wave = threadIdx.x >> 6;
    const int lane = threadIdx.x & 63;
    const int nc = blockIdx.x * 4 + wave;
    const f32x4* xp = reinterpret_cast<const f32x4*>(x + (size_t)nc * HW_);
    f32x4 v[12];
    #pragma unroll
    for (int k = 0; k < 12; ++k) v[k] = xp[lane + k * 64];
    f32x4 vt;
    const bool tail = lane < 16;
    if (tail) vt = xp[768 + lane];
    float a = 0.f, b = 0.f;
    #pragma unroll
    for (int k = 0; k < 12; ++k) {
        a += (v[k].x + v[k].y) + (v[k].z + v[k].w);
        b += (v[k].x * v[k].x + v[k].y * v[k].y) + (v[k].z * v[k].z + v[k].w * v[k].w);
    }
    if (tail) {
        a += (vt.x + vt.y) + (vt.z + vt.w);
        b += (vt.x * vt.x + vt.y * vt.y) + (vt.z * vt.z + vt.w * vt.w);
    }
    #pragma unroll
    for (int off = 32; off; off >>= 1) {
        a += __shfl_down(a, off, 64);
        b += __shfl_down(b, off, 64);
    }
    if (lane == 0) { s1[nc] = a; s2[nc] = b; }
}

// ---------------- Kernel 2: per-channel logits + first-occurrence argmax ----------------
__global__ __launch_bounds__(64) void k_logits(const float* __restrict__ s1,
                                               const float* __restrict__ s2,
                                               const float* __restrict__ fc_w,
                                               const float* __restrict__ fc_b,
                                               int* __restrict__ gidx) {
    const int c = blockIdx.x;
    const int t = threadIdx.x;
    const int g = t & 31, half = t >> 5;
    const float inv_hw  = 1.f / (float)HW_;
    const float inv_hw1 = 1.f / (float)(HW_ - 1);
    const float* wg = fc_w + g * (2 * N_);
    float acc = half ? 0.f : fc_b[g];
    const int n0 = half * 32;
    #pragma unroll 8
    for (int n = n0; n < n0 + 32; ++n) {
        const float v1 = s1[n * C_ + c];
        const float v2 = s2[n * C_ + c];
        const float m  = v1 * inv_hw;
        const float vr = (v2 - v1 * m) * inv_hw1;   // ddof=1
        acc += m * wg[n] + vr * wg[N_ + n];
    }
    acc += __shfl_down(acc, 32, 64);
    __shared__ float lg[G_];
    if (half == 0) lg[g] = acc;
    __syncthreads();
    if (t == 0) {
        float best = lg[0];
        int bi = 0;
        for (int g2 = 1; g2 < G_; ++g2) {
            const float v = lg[g2];
            if (v > best) { best = v; bi = g2; }
        }
        gidx[c] = bi;
    }
}

// ---------------- Kernel 3: group stats (per block, in LDS) + normalize ----------------
// Block b owns slices nc = 4b..4b+3, all sharing n = (4b)>>8 (4 divides 256).
// x loads are issued FIRST so HBM latency hides under the staging/stats work.
__global__ __launch_bounds__(256) void k_norm_g(const float* __restrict__ x,
                                                const float* __restrict__ s1,
                                                const float* __restrict__ s2,
                                                const int* __restrict__ gidx,
                                                const float* __restrict__ weight,
                                                const float* __restrict__ bias,
                                                float* __restrict__ out) {
    const int b    = blockIdx.x;
    const int t    = threadIdx.x;
    const int w    = t >> 6;
    const int lane = t & 63;
    const int nc   = b * 4 + w;
    const int n    = nc >> 8;
    const int c    = nc & (C_ - 1);

    // 1) issue this wave's 13 x loads
    const f32x4* xp = reinterpret_cast<const f32x4*>(x) + (size_t)nc * NV_;
    f32x4 v[12];
    #pragma unroll
    for (int k = 0; k < 12; ++k) v[k] = xp[lane + k * 64];
    f32x4 vt;
    const bool tail = lane < 16;
    if (tail) vt = xp[768 + lane];

    // 2) stage s1/s2 row + gidx, compute group stats
    __shared__ float r1[C_], r2[C_];
    __shared__ int   gi[C_];
    __shared__ float mg[G_], ig[G_];
    r1[t] = s1[n * C_ + t];
    r2[t] = s2[n * C_ + t];
    gi[t] = gidx[t];
    __syncthreads();
    if (t < G_) {
        float A = 0.f, B = 0.f; int k = 0;
        for (int cc = 0; cc < C_; ++cc)
            if (gi[cc] == t) { A += r1[cc]; B += r2[cc]; ++k; }
        const float cf = (float)k * (float)HW_;
        const float m  = A / fmaxf(cf, 1.f);
        const float vr = (B - A * m) / fmaxf(cf - 1.f, 1.f);
        mg[t] = m;
        ig[t] = rsqrtf(vr + EPS_);
    }
    __syncthreads();

    // 3) per-slice fused scale/shift, then normalize + NT stores
    const int g = gi[c];
    const float sc = ig[g] * weight[c];
    const float sh = bias[c] - mg[g] * sc;
    f32x4* op = reinterpret_cast<f32x4*>(out) + (size_t)nc * NV_;
    #pragma unroll
    for (int k = 0; k < 12; ++k)
        __builtin_nontemporal_store(v[k] * sc + sh, op + lane + k * 64);
    if (tail)
        __builtin_nontemporal_store(vt * sc + sh, op + 768 + lane);
}

extern "C" void kernel_launch(void* const* d_in, const int* in_sizes, int n_in,
                              void* d_out, int out_size, void* d_ws, size_t ws_size,
                              hipStream_t stream) {
    const float* x      = (const float*)d_in[0];
    const float* fc_w   = (const float*)d_in[1];
    const float* fc_b   = (const float*)d_in[2];
    const float* weight = (const float*)d_in[3];
    const float* bias   = (const float*)d_in[4];
    float* outp = (float*)d_out;

    float* ws    = (float*)d_ws;
    float* s1    = ws;
    float* s2    = ws + NC_;
    int*   gidxg = (int*)(ws + 2 * NC_);

    k_sums  <<<NC_ / 4, 256, 0, stream>>>(x, s1, s2);
    k_logits<<<C_,       64, 0, stream>>>(s1, s2, fc_w, fc_b, gidxg);
    k_norm_g<<<NC_ / 4, 256, 0, stream>>>(x, s1, s2, gidxg, weight, bias, outp);
}

// Round 10
// 122.732 us; speedup vs baseline: 3.3087x; 1.0466x over previous
//
#include <hip/hip_runtime.h>

constexpr int N_  = 64;
constexpr int C_  = 256;
constexpr int HW_ = 56 * 56;      // 3136 floats per slice
constexpr int NV_ = HW_ / 4;      // 784 f32x4 per slice
constexpr int G_  = 32;
constexpr int NC_ = N_ * C_;      // 16384
constexpr float EPS_ = 1e-5f;

typedef float f32x4 __attribute__((ext_vector_type(4)));

// ---------------- Kernel 1: per-(n,c) sum & sumsq — one wave per slice ----------------
// Regular loads on purpose: this is the allocating read that makes x L3-resident
// so k_norm's re-read stays on-die.
__global__ __launch_bounds__(256) void k_sums(const float* __restrict__ x,
                                              float* __restrict__ s1,
                                              float* __restrict__ s2) {
    const int wave = threadIdx.x >> 6;
    const int lane = threadIdx.x & 63;
    const int nc = blockIdx.x * 4 + wave;
    const f32x4* xp = reinterpret_cast<const f32x4*>(x + (size_t)nc * HW_);
    f32x4 v[12];
    #pragma unroll
    for (int k = 0; k < 12; ++k) v[k] = xp[lane + k * 64];
    f32x4 vt;
    const bool tail = lane < 16;
    if (tail) vt = xp[768 + lane];
    float a = 0.f, b = 0.f;
    #pragma unroll
    for (int k = 0; k < 12; ++k) {
        a += (v[k].x + v[k].y) + (v[k].z + v[k].w);
        b += (v[k].x * v[k].x + v[k].y * v[k].y) + (v[k].z * v[k].z + v[k].w * v[k].w);
    }
    if (tail) {
        a += (vt.x + vt.y) + (vt.z + vt.w);
        b += (vt.x * vt.x + vt.y * vt.y) + (vt.z * vt.z + vt.w * vt.w);
    }
    #pragma unroll
    for (int off = 32; off; off >>= 1) {
        a += __shfl_down(a, off, 64);
        b += __shfl_down(b, off, 64);
    }
    if (lane == 0) { s1[nc] = a; s2[nc] = b; }
}

// ---------------- Kernel 2: per-channel logits + first-occurrence argmax ----------------
__global__ __launch_bounds__(64) void k_logits(const float* __restrict__ s1,
                                               const float* __restrict__ s2,
                                               const float* __restrict__ fc_w,
                                               const float* __restrict__ fc_b,
                                               int* __restrict__ gidx) {
    const int c = blockIdx.x;
    const int t = threadIdx.x;
    const int g = t & 31, half = t >> 5;
    const float inv_hw  = 1.f / (float)HW_;
    const float inv_hw1 = 1.f / (float)(HW_ - 1);
    const float* wg = fc_w + g * (2 * N_);
    float acc = half ? 0.f : fc_b[g];
    const int n0 = half * 32;
    #pragma unroll 8
    for (int n = n0; n < n0 + 32; ++n) {
        const float v1 = s1[n * C_ + c];
        const float v2 = s2[n * C_ + c];
        const float m  = v1 * inv_hw;
        const float vr = (v2 - v1 * m) * inv_hw1;   // ddof=1
        acc += m * wg[n] + vr * wg[N_ + n];
    }
    acc += __shfl_down(acc, 32, 64);
    __shared__ float lg[G_];
    if (half == 0) lg[g] = acc;
    __syncthreads();
    if (t == 0) {
        float best = lg[0];
        int bi = 0;
        for (int g2 = 1; g2 < G_; ++g2) {
            const float v = lg[g2];
            if (v > best) { best = v; bi = g2; }
        }
        gidx[c] = bi;
    }
}

// ---------------- Kernel 3: per-n group stats -> fused scale/shift ----------------
__global__ __launch_bounds__(256) void k_group(const float* __restrict__ s1,
                                               const float* __restrict__ s2,
                                               const int* __restrict__ gidx,
                                               const float* __restrict__ weight,
                                               const float* __restrict__ bias,
                                               float* __restrict__ scale,
                                               float* __restrict__ shift) {
    const int n = blockIdx.x;
    const int c = threadIdx.x;
    __shared__ float r1[C_], r2[C_];
    __shared__ int   gi[C_];
    __shared__ float mg[G_], ig[G_];
    r1[c] = s1[n * C_ + c];
    r2[c] = s2[n * C_ + c];
    gi[c] = gidx[c];
    __syncthreads();
    if (c < G_) {
        float A = 0.f, B = 0.f;
        int k = 0;
        for (int cc = 0; cc < C_; ++cc) {
            if (gi[cc] == c) { A += r1[cc]; B += r2[cc]; ++k; }
        }
        const float cf = (float)k * (float)HW_;
        const float m  = A / fmaxf(cf, 1.f);
        const float vr = (B - A * m) / fmaxf(cf - 1.f, 1.f);
        mg[c] = m;
        ig[c] = rsqrtf(vr + EPS_);
    }
    __syncthreads();
    const int g = gi[c];
    const float sc = ig[g] * weight[c];
    scale[n * C_ + c] = sc;
    shift[n * C_ + c] = bias[c] - mg[g] * sc;
}

// ---------------- Kernel 4: normalize — one wave per slice ----------------
// NT loads (x is dead after this; L3 gets wiped by the harness fill anyway)
// and NT stores, interleaved per-vector so the write stream drains early.
__global__ __launch_bounds__(256) void k_norm(const float* __restrict__ x,
                                              const float* __restrict__ scale,
                                              const float* __restrict__ shift,
                                              float* __restrict__ out) {
    const int wave = threadIdx.x >> 6;
    const int lane = threadIdx.x & 63;
    const int nc = blockIdx.x * 4 + wave;
    const float sc = scale[nc];
    const float sh = shift[nc];
    const f32x4* xp = reinterpret_cast<const f32x4*>(x + (size_t)nc * HW_);
    f32x4* op = reinterpret_cast<f32x4*>(out + (size_t)nc * HW_);
    #pragma unroll
    for (int k = 0; k < 12; ++k) {
        f32x4 v = __builtin_nontemporal_load(xp + lane + k * 64);
        __builtin_nontemporal_store(v * sc + sh, op + lane + k * 64);
    }
    if (lane < 16) {
        f32x4 v = __builtin_nontemporal_load(xp + 768 + lane);
        __builtin_nontemporal_store(v * sc + sh, op + 768 + lane);
    }
}

extern "C" void kernel_launch(void* const* d_in, const int* in_sizes, int n_in,
                              void* d_out, int out_size, void* d_ws, size_t ws_size,
                              hipStream_t stream) {
    const float* x      = (const float*)d_in[0];
    const float* fc_w   = (const float*)d_in[1];
    const float* fc_b   = (const float*)d_in[2];
    const float* weight = (const float*)d_in[3];
    const float* bias   = (const float*)d_in[4];
    float* outp = (float*)d_out;

    float* ws    = (float*)d_ws;
    float* s1    = ws;
    float* s2    = ws + NC_;
    float* scale = ws + 2 * NC_;
    float* shift = ws + 3 * NC_;
    int*   gidxg = (int*)(ws + 4 * NC_);

    k_sums  <<<NC_ / 4, 256, 0, stream>>>(x, s1, s2);
    k_logits<<<C_,       64, 0, stream>>>(s1, s2, fc_w, fc_b, gidxg);
    k_group <<<N_,      256, 0, stream>>>(s1, s2, gidxg, weight, bias, scale, shift);
    k_norm  <<<NC_ / 4, 256, 0, stream>>>(x, scale, shift, outp);
}